// Round 4
// baseline (1553.043 us; speedup 1.0000x reference)
//
#include <hip/hip_runtime.h>
#include <hip/hip_bf16.h>

typedef unsigned short u16;
typedef unsigned int u32;
typedef __attribute__((ext_vector_type(4))) float fx4;
typedef __attribute__((ext_vector_type(8))) __bf16 bf8;

#define NEGV -1e9f
#define SCALE_ 0.17677669529663687f

static __device__ __forceinline__ u16 f2bu(float f){
    __hip_bfloat16 h = __float2bfloat16(f);
    return *reinterpret_cast<u16*>(&h);
}
static __device__ __forceinline__ float b2f(u16 u){
    __hip_bfloat16 h;
    *reinterpret_cast<u16*>(&h) = u;
    return __bfloat162float(h);
}

// ---- K0: fp32 -> bf16 conversion of all 4 weight matrices, one launch ----
__global__ __launch_bounds__(256) void f2b4_kernel(
        const float* __restrict__ s0, const float* __restrict__ s1,
        const float* __restrict__ s2, const float* __restrict__ s3,
        u16* __restrict__ d0, u16* __restrict__ d1,
        u16* __restrict__ d2, u16* __restrict__ d3){
    int i = blockIdx.x*256 + threadIdx.x;
    if (i < 110592) d0[i] = f2bu(s0[i]);
    if (i < 36864)  d1[i] = f2bu(s1[i]);
    if (i < 147456){ d2[i] = f2bu(s2[i]); d3[i] = f2bu(s3[i]); }
}

// ---- K1: roll(-3,-3) + window partition + LN1 ----
__global__ __launch_bounds__(256) void partition_ln_kernel(
        const float* __restrict__ x, const float* __restrict__ g, const float* __restrict__ bta,
        u16* __restrict__ xw, u16* __restrict__ y){
    __shared__ float lds[192*57];
    const int bi = blockIdx.x;
    const int b = bi/56, i = bi%56;
    const int si = (i+3)%56;
    const float* src = x + (size_t)b*602112 + (size_t)si*56;
    for (int e = threadIdx.x; e < 10752; e += 256){
        int c = e/56, j = e%56;
        lds[c*57 + j] = src[(size_t)c*3136 + j];
    }
    __syncthreads();
    const int wrow_base = (b*8 + i/7)*8;
    const int prow = (i%7)*7;
    for (int e = threadIdx.x; e < 10752; e += 256){
        int j = e/192, c = e%192;
        int t = (wrow_base + j/7)*49 + prow + (j%7);
        xw[(size_t)t*192 + c] = f2bu(lds[c*57 + (j+3)%56]);
    }
    const int wv = threadIdx.x>>6, l = threadIdx.x&63;
    for (int j = wv; j < 56; j += 4){
        const int jj = (j+3)%56;
        float v0 = lds[l*57 + jj], v1 = lds[(l+64)*57 + jj], v2 = lds[(l+128)*57 + jj];
        float s = v0+v1+v2;
        #pragma unroll
        for (int o=32;o;o>>=1) s += __shfl_xor(s, o, 64);
        const float mean = s*(1.f/192.f);
        float d0 = v0-mean, d1 = v1-mean, d2 = v2-mean;
        float qv = d0*d0 + d1*d1 + d2*d2;
        #pragma unroll
        for (int o=32;o;o>>=1) qv += __shfl_xor(qv, o, 64);
        const float rstd = rsqrtf(qv*(1.f/192.f) + 1e-5f);
        const int t = (wrow_base + j/7)*49 + prow + (j%7);
        u16* yr = y + (size_t)t*192;
        yr[l]     = f2bu(d0*rstd*g[l]     + bta[l]);
        yr[l+64]  = f2bu(d1*rstd*g[l+64]  + bta[l+64]);
        yr[l+128] = f2bu(d2*rstd*g[l+128] + bta[l+128]);
    }
}

// ---- K9: window reverse + roll(+3,+3) ----
__global__ __launch_bounds__(256) void reverse_kernel(const float* __restrict__ xw, float* __restrict__ out){
    __shared__ float lds[192*57];
    const int bi = blockIdx.x;
    const int b = bi/56, h = bi%56;
    const int i = (h+53)%56;
    const int wrow_base = (b*8 + i/7)*8;
    const int prow = (i%7)*7;
    for (int e = threadIdx.x; e < 10752; e += 256){
        int j = e/192, c = e%192;
        int t = (wrow_base + j/7)*49 + prow + (j%7);
        lds[c*57 + j] = xw[(size_t)t*192 + c];
    }
    __syncthreads();
    float* dst = out + (size_t)b*602112 + (size_t)h*56;
    for (int e = threadIdx.x; e < 10752; e += 256){
        int c = e/56, w = e%56;
        dst[(size_t)c*3136 + w] = lds[c*57 + (w+53)%56];
    }
}

// ---- B-stationary register GEMM ----
// 4 waves/block; wave wv owns 48 cols (3 col-tiles), col0 = blockIdx.y*192 + wv*48.
// B fragments live in 72 VGPRs (per 192-K chunk), loaded from L2-hot weights.
// Grid-stride over M in 32-row tiles. Zero LDS/barriers in main loop (LNOUT adds
// a 1KB cross-wave reduce). K = KCH*192.
template<int KCH,int ACT,int RES,int LNOUT,int OUTBF,int HASB>
__global__ __launch_bounds__(256,3) void gemm_kernel(
    const u16* __restrict__ A, const u16* __restrict__ Bw,
    const float* __restrict__ bias, const u16* __restrict__ res,
    void* __restrict__ out,
    const float* __restrict__ lng, const float* __restrict__ lnb,
    u16* __restrict__ yout, int Ntot, int mtiles)
{
    constexpr int K = KCH*192;
    __shared__ float redS[4][32][2];
    const int tid = threadIdx.x;
    const int wv = tid>>6, l = tid&63, lr = l&15, lg = l>>4;
    const int col0 = blockIdx.y*192 + wv*48;

    bf8 breg[3][6];
    if (KCH == 1){
        #pragma unroll
        for (int c=0;c<3;c++)
            #pragma unroll
            for (int kk=0;kk<6;kk++)
                breg[c][kk] = *(const bf8*)(Bw + (size_t)(col0+c*16+lr)*K + kk*32 + lg*8);
    }

    for (int it = blockIdx.x; it < mtiles; it += gridDim.x){
        const size_t row0 = (size_t)it*32;
        fx4 acc[2][3] = {};
        #pragma unroll
        for (int kc=0; kc<KCH; ++kc){
            if (KCH > 1){
                #pragma unroll
                for (int c=0;c<3;c++)
                    #pragma unroll
                    for (int kk=0;kk<6;kk++)
                        breg[c][kk] = *(const bf8*)(Bw + (size_t)(col0+c*16+lr)*K + kc*192 + kk*32 + lg*8);
            }
            #pragma unroll
            for (int kk=0;kk<6;kk++){
                bf8 af0 = *(const bf8*)(A + (row0 + lr)*K      + kc*192 + kk*32 + lg*8);
                bf8 af1 = *(const bf8*)(A + (row0 + 16 + lr)*K + kc*192 + kk*32 + lg*8);
                #pragma unroll
                for (int c=0;c<3;c++){
                    acc[0][c] = __builtin_amdgcn_mfma_f32_16x16x32_bf16(af0, breg[c][kk], acc[0][c], 0,0,0);
                    acc[1][c] = __builtin_amdgcn_mfma_f32_16x16x32_bf16(af1, breg[c][kk], acc[1][c], 0,0,0);
                }
            }
        }
        // epilogue: bias/act/res + store
        #pragma unroll
        for (int r=0;r<2;r++)
            #pragma unroll
            for (int c=0;c<3;c++){
                const int col = col0 + c*16 + lr;
                const float bv = HASB ? bias[col] : 0.f;
                #pragma unroll
                for (int q=0;q<4;q++){
                    const size_t grow = row0 + r*16 + lg*4 + q;
                    float v = acc[r][c][q] + bv;
                    if (ACT) v = 0.5f*v*(1.f + erff(v*0.70710678118654752f));
                    if (RES) v += b2f(res[grow*Ntot + col]);
                    acc[r][c][q] = v;
                    if (OUTBF) ((u16*)out)[grow*Ntot + col] = f2bu(v);
                    else       ((float*)out)[grow*Ntot + col] = v;
                }
            }
        if (LNOUT){
            // cross-wave LN over 192 cols (4 waves x 48)
            #pragma unroll
            for (int r=0;r<2;r++)
                #pragma unroll
                for (int q=0;q<4;q++){
                    float s  = acc[r][0][q] + acc[r][1][q] + acc[r][2][q];
                    float s2 = acc[r][0][q]*acc[r][0][q] + acc[r][1][q]*acc[r][1][q] + acc[r][2][q]*acc[r][2][q];
                    #pragma unroll
                    for (int o=8;o;o>>=1){ s += __shfl_xor(s, o, 64); s2 += __shfl_xor(s2, o, 64); }
                    if (lr == 0){
                        redS[wv][r*16 + lg*4 + q][0] = s;
                        redS[wv][r*16 + lg*4 + q][1] = s2;
                    }
                }
            __syncthreads();
            float meanv[2][4], rstdv[2][4];
            #pragma unroll
            for (int r=0;r<2;r++)
                #pragma unroll
                for (int q=0;q<4;q++){
                    const int row = r*16 + lg*4 + q;
                    float S = 0.f, S2 = 0.f;
                    #pragma unroll
                    for (int ww=0;ww<4;ww++){ S += redS[ww][row][0]; S2 += redS[ww][row][1]; }
                    const float mean = S*(1.f/192.f);
                    const float var = S2*(1.f/192.f) - mean*mean;
                    meanv[r][q] = mean;
                    rstdv[r][q] = rsqrtf(var + 1e-5f);
                }
            __syncthreads();
            #pragma unroll
            for (int r=0;r<2;r++)
                #pragma unroll
                for (int c=0;c<3;c++){
                    const int col = col0 + c*16 + lr;
                    const float gc = lng[col], bc = lnb[col];
                    #pragma unroll
                    for (int q=0;q<4;q++){
                        const size_t grow = row0 + r*16 + lg*4 + q;
                        yout[grow*192 + col] = f2bu((acc[r][c][q]-meanv[r][q])*rstdv[r][q]*gc + bc);
                    }
                }
        }
    }
}

// ---- attention: one wave per (window, head) ----
__global__ __launch_bounds__(64) void attn_kernel(const u16* __restrict__ qkv,
                                                  const float* __restrict__ rel_table,
                                                  u16* __restrict__ o)
{
    __shared__ u16 pa[64*72];
    __shared__ u16 vt[32*72];
    const int bid = blockIdx.x;
    const int widx = bid/6, h = bid - widx*6;
    const int wi = widx & 63;
    const int nhi = wi>>3, nwi = wi&7;
    const int l = threadIdx.x, lr = l&15, lg = l>>4;
    const u16* base = qkv + (size_t)widx*49*576;

    bf8 qf[4], kf[4];
    #pragma unroll
    for (int t=0;t<4;t++){
        const int row = min(t*16 + lr, 48);
        qf[t] = *(const bf8*)(base + (size_t)row*576 + h*32 + lg*8);
        kf[t] = *(const bf8*)(base + (size_t)row*576 + 192 + h*32 + lg*8);
    }
    for (int e=l; e<480; e+=64){
        int d = e/15, j = 49 + (e - d*15);
        vt[d*72 + j] = 0;
    }
    for (int e=l; e<784; e+=64){
        int j = e>>4, dp = e&15;
        u32 val = *(const u32*)(base + (size_t)j*576 + 384 + h*32 + dp*2);
        vt[(dp*2)*72 + j]   = (u16)(val & 0xffffu);
        vt[(dp*2+1)*72 + j] = (u16)(val >> 16);
    }

    fx4 acc[4][4] = {};
    #pragma unroll
    for (int ti=0;ti<4;ti++)
        #pragma unroll
        for (int tj=0;tj<4;tj++)
            acc[ti][tj] = __builtin_amdgcn_mfma_f32_16x16x32_bf16(qf[ti], kf[tj], acc[ti][tj], 0,0,0);

    int jdiv[4], jmod[4], mj[4];
    #pragma unroll
    for (int tj=0;tj<4;tj++){
        const int j = tj*16 + lr;
        if (j < 49){
            const int jd = j/7, jm = j - jd*7;
            jdiv[tj]=jd; jmod[tj]=jm;
            const int gh = nhi*7 + jd, gw = nwi*7 + jm;
            mj[tj] = (gh<49?0:(gh<53?1:2))*3 + (gw<49?0:(gw<53?1:2));
        } else { jdiv[tj]=0; jmod[tj]=0; mj[tj] = -1; }
    }
    #pragma unroll
    for (int ti=0;ti<4;ti++){
        #pragma unroll
        for (int reg=0;reg<4;reg++){
            const int i = ti*16 + lg*4 + reg;
            int id=0, im=0, mi=-2;
            if (i < 49){
                id = i/7; im = i - id*7;
                const int gh = nhi*7 + id, gw = nwi*7 + im;
                mi = (gh<49?0:(gh<53?1:2))*3 + (gw<49?0:(gw<53?1:2));
            }
            #pragma unroll
            for (int tj=0;tj<4;tj++){
                const int j = tj*16 + lr;
                float lv = NEGV;
                if (i < 49 && j < 49){
                    const int ridx = (id - jdiv[tj] + 6)*13 + (im - jmod[tj] + 6);
                    lv = acc[ti][tj][reg]*SCALE_ + rel_table[ridx*6 + h]
                       + ((mi == mj[tj]) ? 0.f : NEGV);
                }
                acc[ti][tj][reg] = lv;
            }
        }
    }
    #pragma unroll
    for (int ti=0;ti<4;ti++){
        #pragma unroll
        for (int reg=0;reg<4;reg++){
            float mx = fmaxf(fmaxf(acc[ti][0][reg], acc[ti][1][reg]),
                             fmaxf(acc[ti][2][reg], acc[ti][3][reg]));
            #pragma unroll
            for (int o2=8;o2;o2>>=1) mx = fmaxf(mx, __shfl_xor(mx, o2, 64));
            float sum = 0.f;
            #pragma unroll
            for (int tj=0;tj<4;tj++){
                float p = __expf(acc[ti][tj][reg] - mx);
                acc[ti][tj][reg] = p;
                sum += p;
            }
            #pragma unroll
            for (int o2=8;o2;o2>>=1) sum += __shfl_xor(sum, o2, 64);
            const float rs = 1.f/sum;
            #pragma unroll
            for (int tj=0;tj<4;tj++) acc[ti][tj][reg] *= rs;
        }
    }
    #pragma unroll
    for (int ti=0;ti<4;ti++)
        #pragma unroll
        for (int tj=0;tj<4;tj++)
            #pragma unroll
            for (int reg=0;reg<4;reg++)
                pa[(ti*16 + lg*4 + reg)*72 + tj*16 + lr] = f2bu(acc[ti][tj][reg]);
    __syncthreads();

    fx4 oacc[4][2] = {};
    #pragma unroll
    for (int kk=0;kk<2;kk++){
        bf8 bfr[2];
        #pragma unroll
        for (int cd=0;cd<2;cd++)
            bfr[cd] = *(const bf8*)(vt + (cd*16+lr)*72 + kk*32 + lg*8);
        #pragma unroll
        for (int ti=0;ti<4;ti++){
            bf8 afr = *(const bf8*)(pa + (ti*16+lr)*72 + kk*32 + lg*8);
            #pragma unroll
            for (int cd=0;cd<2;cd++)
                oacc[ti][cd] = __builtin_amdgcn_mfma_f32_16x16x32_bf16(afr, bfr[cd], oacc[ti][cd], 0,0,0);
        }
    }
    u16* ob = o + (size_t)widx*49*192 + h*32;
    #pragma unroll
    for (int ti=0;ti<4;ti++)
        #pragma unroll
        for (int cd=0;cd<2;cd++)
            #pragma unroll
            for (int q=0;q<4;q++){
                const int i = ti*16 + lg*4 + q;
                if (i < 49) ob[(size_t)i*192 + cd*16 + lr] = f2bu(oacc[ti][cd][q]);
            }
}

extern "C" void kernel_launch(void* const* d_in, const int* in_sizes, int n_in,
                              void* d_out, int out_size, void* d_ws, size_t ws_size,
                              hipStream_t stream)
{
    const float* x      = (const float*)d_in[0];
    const float* ln1_g  = (const float*)d_in[1];
    const float* ln1_b  = (const float*)d_in[2];
    const float* qkv_w  = (const float*)d_in[3];
    const float* out_w  = (const float*)d_in[4];
    const float* out_b  = (const float*)d_in[5];
    const float* ln2_g  = (const float*)d_in[6];
    const float* ln2_b  = (const float*)d_in[7];
    const float* mlp_w1 = (const float*)d_in[8];
    const float* mlp_b1 = (const float*)d_in[9];
    const float* mlp_w2 = (const float*)d_in[10];
    const float* mlp_b2 = (const float*)d_in[11];
    const float* rel_t  = (const float*)d_in[12];

    char* ws = (char*)d_ws;
    u16*   Ybuf = (u16*)ws;                     // y / O / y2 bf16 [T,192]; later xw3 f32
    float* OutF = (float*)ws;
    u16*   XWbuf = (u16*)(ws + 154140672);      // xw / xw2 bf16 [T,192]
    u16*   QKVH  = (u16*)(ws + 231211008);      // qkv [T,576] then h [T,768] bf16
    u16*   Wq = (u16*)(ws + 539492352);
    u16*   Wo = Wq + 110592;
    u16*   W1 = Wo + 36864;
    u16*   W2 = W1 + 147456;

    f2b4_kernel<<<576,256,0,stream>>>(qkv_w, out_w, mlp_w1, mlp_w2, Wq, Wo, W1, W2);

    // partition + LN1
    partition_ln_kernel<<<3584,256,0,stream>>>(x, ln1_g, ln1_b, XWbuf, Ybuf);
    // qkv = y @ Wq^T : [T,576] bf16
    gemm_kernel<1,0,0,0,1,0><<<dim3(1568,3),256,0,stream>>>(Ybuf, Wq, nullptr, nullptr, QKVH,
                                                            nullptr, nullptr, nullptr, 576, 6272);
    attn_kernel<<<24576,64,0,stream>>>(QKVH, rel_t, Ybuf);
    // xw2 = xw + O @ Wo^T + b (bf16, in-place XW); y2 = LN2(xw2) -> Ybuf
    gemm_kernel<1,0,1,1,1,1><<<dim3(1568,1),256,0,stream>>>(Ybuf, Wo, out_b, XWbuf, XWbuf,
                                                            ln2_g, ln2_b, Ybuf, 192, 6272);
    // h = gelu(y2 @ W1^T + b1) : [T,768] bf16
    gemm_kernel<1,1,0,0,1,1><<<dim3(1568,4),256,0,stream>>>(Ybuf, W1, mlp_b1, nullptr, QKVH,
                                                            nullptr, nullptr, nullptr, 768, 6272);
    // xw3 = xw2 + h @ W2^T + b2 : f32 -> OutF
    gemm_kernel<4,0,1,0,0,1><<<dim3(1568,1),256,0,stream>>>(QKVH, W2, mlp_b2, XWbuf, OutF,
                                                            nullptr, nullptr, nullptr, 192, 6272);
    reverse_kernel<<<3584,256,0,stream>>>(OutF, (float*)d_out);
}

// Round 5
// 895.128 us; speedup vs baseline: 1.7350x; 1.7350x over previous
//
#include <hip/hip_runtime.h>
#include <hip/hip_bf16.h>

typedef unsigned short u16;
typedef unsigned int u32;
typedef __attribute__((ext_vector_type(4))) float fx4;
typedef __attribute__((ext_vector_type(8))) __bf16 bf8;

#define NEGV -1e9f
#define SCALE_ 0.17677669529663687f

static __device__ __forceinline__ u16 f2bu(float f){
    __hip_bfloat16 h = __float2bfloat16(f);
    return *reinterpret_cast<u16*>(&h);
}
static __device__ __forceinline__ float b2f(u16 u){
    __hip_bfloat16 h;
    *reinterpret_cast<u16*>(&h) = u;
    return __bfloat162float(h);
}

// ---- K0: fp32 -> bf16 conversion of all 4 weight matrices ----
__global__ __launch_bounds__(256) void f2b4_kernel(
        const float* __restrict__ s0, const float* __restrict__ s1,
        const float* __restrict__ s2, const float* __restrict__ s3,
        u16* __restrict__ d0, u16* __restrict__ d1,
        u16* __restrict__ d2, u16* __restrict__ d3){
    int i = blockIdx.x*256 + threadIdx.x;
    if (i < 110592) d0[i] = f2bu(s0[i]);
    if (i < 36864)  d1[i] = f2bu(s1[i]);
    if (i < 147456){ d2[i] = f2bu(s2[i]); d3[i] = f2bu(s3[i]); }
}

// ---- K1: roll(-3,-3) + window partition + LN1 ----
__global__ __launch_bounds__(256) void partition_ln_kernel(
        const float* __restrict__ x, const float* __restrict__ g, const float* __restrict__ bta,
        u16* __restrict__ xw, u16* __restrict__ y){
    __shared__ float lds[192*57];
    const int bi = blockIdx.x;
    const int b = bi/56, i = bi%56;
    const int si = (i+3)%56;
    const float* src = x + (size_t)b*602112 + (size_t)si*56;
    for (int e = threadIdx.x; e < 10752; e += 256){
        int c = e/56, j = e%56;
        lds[c*57 + j] = src[(size_t)c*3136 + j];
    }
    __syncthreads();
    const int wrow_base = (b*8 + i/7)*8;
    const int prow = (i%7)*7;
    for (int e = threadIdx.x; e < 10752; e += 256){
        int j = e/192, c = e%192;
        int t = (wrow_base + j/7)*49 + prow + (j%7);
        xw[(size_t)t*192 + c] = f2bu(lds[c*57 + (j+3)%56]);
    }
    const int wv = threadIdx.x>>6, l = threadIdx.x&63;
    for (int j = wv; j < 56; j += 4){
        const int jj = (j+3)%56;
        float v0 = lds[l*57 + jj], v1 = lds[(l+64)*57 + jj], v2 = lds[(l+128)*57 + jj];
        float s = v0+v1+v2;
        #pragma unroll
        for (int o=32;o;o>>=1) s += __shfl_xor(s, o, 64);
        const float mean = s*(1.f/192.f);
        float d0 = v0-mean, d1 = v1-mean, d2 = v2-mean;
        float qv = d0*d0 + d1*d1 + d2*d2;
        #pragma unroll
        for (int o=32;o;o>>=1) qv += __shfl_xor(qv, o, 64);
        const float rstd = rsqrtf(qv*(1.f/192.f) + 1e-5f);
        const int t = (wrow_base + j/7)*49 + prow + (j%7);
        u16* yr = y + (size_t)t*192;
        yr[l]     = f2bu(d0*rstd*g[l]     + bta[l]);
        yr[l+64]  = f2bu(d1*rstd*g[l+64]  + bta[l+64]);
        yr[l+128] = f2bu(d2*rstd*g[l+128] + bta[l+128]);
    }
}

// ---- K9: window reverse + roll(+3,+3) ----
__global__ __launch_bounds__(256) void reverse_kernel(const float* __restrict__ xw, float* __restrict__ out){
    __shared__ float lds[192*57];
    const int bi = blockIdx.x;
    const int b = bi/56, h = bi%56;
    const int i = (h+53)%56;
    const int wrow_base = (b*8 + i/7)*8;
    const int prow = (i%7)*7;
    for (int e = threadIdx.x; e < 10752; e += 256){
        int j = e/192, c = e%192;
        int t = (wrow_base + j/7)*49 + prow + (j%7);
        lds[c*57 + j] = xw[(size_t)t*192 + c];
    }
    __syncthreads();
    float* dst = out + (size_t)b*602112 + (size_t)h*56;
    for (int e = threadIdx.x; e < 10752; e += 256){
        int c = e/56, w = e%56;
        dst[(size_t)c*3136 + w] = lds[c*57 + (w+53)%56];
    }
}

// ---- staging: global -> LDS, 64-K-wide tile (128B/row), XOR-pre-swizzled source ----
// LDS layout: linear [ROWS][128B]; logical value G[row][b] lands at LDS[row][b ^ ((row&7)<<4)]
template<int ROWS>
static __device__ __forceinline__ void stage_tile(const u16* __restrict__ g, size_t grow0,
                                                  int kc, int KE, u16* ldsbase, int tid){
    const int w = tid>>6, lane = tid&63;
    const int sub = lane>>3;                 // row&7 for this lane
    const int b16 = (lane&7) ^ sub;          // 16B unit within 128B row (inverse swizzle)
    #pragma unroll
    for (int i=0; i<ROWS/32; ++i){
        const int row = i*32 + w*8 + sub;
        const u16* src = g + (grow0+row)*(size_t)KE + kc*64 + b16*8;
        u16* dst = ldsbase + i*2048 + w*512;                 // wave-uniform (bytes: i*4096 + w*1024)
#if __has_builtin(__builtin_amdgcn_global_load_lds)
        __builtin_amdgcn_global_load_lds(
            (const __attribute__((address_space(1))) u32*)src,
            (__attribute__((address_space(3))) u32*)dst, 16, 0, 0);
#else
        *(uint4*)(dst + lane*8) = *(const uint4*)src;
#endif
    }
}

// read one MFMA A/B fragment from swizzled LDS tile
static __device__ __forceinline__ bf8 rd_frag(const u16* lds, int row, int bbu){
    // bbu = u16 offset within 64-elem row (multiple of 8)
    return *(const bf8*)(lds + row*64 + (bbu ^ ((row&7)<<3)));
}

// ---- pipelined GEMM: out[M,N] = epi(A[M,K]bf16 @ Bw[N,K]^T bf16) ----
// BM=128, BN=192, BK=64, double-buffered global_load_lds staging.
// 4 waves (2 row x 2 col): wave = 64 rows x 96 cols, acc[4][6].
template<int NK,int ACT,int RES,int LNOUT,int OUTBF,int HASB>
__global__ __launch_bounds__(256,2) void gemm_kernel(
    const u16* __restrict__ A, const u16* __restrict__ Bw,
    const float* __restrict__ bias, const u16* __restrict__ res,
    void* __restrict__ out,
    const float* __restrict__ lng, const float* __restrict__ lnb,
    u16* __restrict__ yout, int Ntot)
{
    const int K = NK*64;
    __shared__ __align__(16) u16 lds[40960];   // 80KB: A0|A1 (16KB ea), B0|B1 (24KB ea)
    const int tid = threadIdx.x;
    const int wv = tid>>6, l = tid&63, lr = l&15, lg = l>>4;
    const int wm = wv&1, wn = wv>>1;
    const size_t row0 = (size_t)blockIdx.x*128;
    const int n0 = blockIdx.y*192;
    const u16* Bblk = Bw + (size_t)n0*K;

    stage_tile<128>(A, row0, 0, K, lds, tid);
    stage_tile<192>(Bblk, 0, 0, K, lds+16384, tid);
    __syncthreads();

    fx4 acc[4][6] = {};
    for (int kc=0; kc<NK; ++kc){
        const int cur = kc & 1;
        u16* Ac = cur ? (u16*)lds+8192  : (u16*)lds;
        u16* Bc = cur ? (u16*)lds+28672 : (u16*)lds+16384;
        if (kc+1 < NK){
            u16* An = cur ? (u16*)lds       : (u16*)lds+8192;
            u16* Bn = cur ? (u16*)lds+16384 : (u16*)lds+28672;
            stage_tile<128>(A, row0, kc+1, K, An, tid);
            stage_tile<192>(Bblk, 0, kc+1, K, Bn, tid);
        }
        #pragma unroll
        for (int kk=0; kk<2; ++kk){
            bf8 af[4], bfr[6];
            #pragma unroll
            for (int r=0;r<4;r++) af[r]  = rd_frag(Ac, wm*64 + r*16 + lr, kk*32 + lg*8);
            #pragma unroll
            for (int c=0;c<6;c++) bfr[c] = rd_frag(Bc, wn*96 + c*16 + lr, kk*32 + lg*8);
            #pragma unroll
            for (int r=0;r<4;r++)
                #pragma unroll
                for (int c=0;c<6;c++)
                    acc[r][c] = __builtin_amdgcn_mfma_f32_16x16x32_bf16(af[r], bfr[c], acc[r][c], 0,0,0);
        }
        __syncthreads();
    }

    // epilogue
    #pragma unroll
    for (int r=0;r<4;r++)
        #pragma unroll
        for (int c=0;c<6;c++){
            const int col = n0 + wn*96 + c*16 + lr;
            const float bv = HASB ? bias[col] : 0.f;
            #pragma unroll
            for (int q=0;q<4;q++){
                const size_t grow = row0 + wm*64 + r*16 + lg*4 + q;
                float v = acc[r][c][q] + bv;
                if (ACT) v = 0.5f*v*(1.f + erff(v*0.70710678118654752f));
                if (RES) v += b2f(res[grow*Ntot + col]);
                acc[r][c][q] = v;
                if (OUTBF) ((u16*)out)[grow*Ntot + col] = f2bu(v);
                else       ((float*)out)[grow*Ntot + col] = v;
            }
        }
    if (LNOUT){
        // LN over 192 cols; combine the two col-waves via LDS (alias staging buffer)
        float* redS = (float*)lds;     // [2][128][2] floats = 2KB
        #pragma unroll
        for (int r=0;r<4;r++)
            #pragma unroll
            for (int q=0;q<4;q++){
                float s  = 0.f, s2 = 0.f;
                #pragma unroll
                for (int c=0;c<6;c++){ float v = acc[r][c][q]; s += v; s2 += v*v; }
                #pragma unroll
                for (int o=8;o;o>>=1){ s += __shfl_xor(s, o, 64); s2 += __shfl_xor(s2, o, 64); }
                if (lr == 0){
                    const int rowl = wm*64 + r*16 + lg*4 + q;
                    redS[(wn*128 + rowl)*2 + 0] = s;
                    redS[(wn*128 + rowl)*2 + 1] = s2;
                }
            }
        __syncthreads();
        #pragma unroll
        for (int r=0;r<4;r++)
            #pragma unroll
            for (int q=0;q<4;q++){
                const int rowl = wm*64 + r*16 + lg*4 + q;
                const float S  = redS[rowl*2+0] + redS[(128+rowl)*2+0];
                const float S2 = redS[rowl*2+1] + redS[(128+rowl)*2+1];
                const float mean = S*(1.f/192.f);
                const float rstd = rsqrtf(S2*(1.f/192.f) - mean*mean + 1e-5f);
                const size_t grow = row0 + rowl;
                #pragma unroll
                for (int c=0;c<6;c++){
                    const int col = wn*96 + c*16 + lr;
                    yout[grow*192 + col] = f2bu((acc[r][c][q]-mean)*rstd*lng[col] + lnb[col]);
                }
            }
    }
}

// ---- attention: one wave per (window, head) ----
__global__ __launch_bounds__(64) void attn_kernel(const u16* __restrict__ qkv,
                                                  const float* __restrict__ rel_table,
                                                  u16* __restrict__ o)
{
    __shared__ u16 pa[64*72];
    __shared__ u16 vt[32*72];
    const int bid = blockIdx.x;
    const int widx = bid/6, h = bid - widx*6;
    const int wi = widx & 63;
    const int nhi = wi>>3, nwi = wi&7;
    const int l = threadIdx.x, lr = l&15, lg = l>>4;
    const u16* base = qkv + (size_t)widx*49*576;

    bf8 qf[4], kf[4];
    #pragma unroll
    for (int t=0;t<4;t++){
        const int row = min(t*16 + lr, 48);
        qf[t] = *(const bf8*)(base + (size_t)row*576 + h*32 + lg*8);
        kf[t] = *(const bf8*)(base + (size_t)row*576 + 192 + h*32 + lg*8);
    }
    for (int e=l; e<480; e+=64){
        int d = e/15, j = 49 + (e - d*15);
        vt[d*72 + j] = 0;
    }
    for (int e=l; e<784; e+=64){
        int j = e>>4, dp = e&15;
        u32 val = *(const u32*)(base + (size_t)j*576 + 384 + h*32 + dp*2);
        vt[(dp*2)*72 + j]   = (u16)(val & 0xffffu);
        vt[(dp*2+1)*72 + j] = (u16)(val >> 16);
    }

    fx4 acc[4][4] = {};
    #pragma unroll
    for (int ti=0;ti<4;ti++)
        #pragma unroll
        for (int tj=0;tj<4;tj++)
            acc[ti][tj] = __builtin_amdgcn_mfma_f32_16x16x32_bf16(qf[ti], kf[tj], acc[ti][tj], 0,0,0);

    int jdiv[4], jmod[4], mj[4];
    #pragma unroll
    for (int tj=0;tj<4;tj++){
        const int j = tj*16 + lr;
        if (j < 49){
            const int jd = j/7, jm = j - jd*7;
            jdiv[tj]=jd; jmod[tj]=jm;
            const int gh = nhi*7 + jd, gw = nwi*7 + jm;
            mj[tj] = (gh<49?0:(gh<53?1:2))*3 + (gw<49?0:(gw<53?1:2));
        } else { jdiv[tj]=0; jmod[tj]=0; mj[tj] = -1; }
    }
    #pragma unroll
    for (int ti=0;ti<4;ti++){
        #pragma unroll
        for (int reg=0;reg<4;reg++){
            const int i = ti*16 + lg*4 + reg;
            int id=0, im=0, mi=-2;
            if (i < 49){
                id = i/7; im = i - id*7;
                const int gh = nhi*7 + id, gw = nwi*7 + im;
                mi = (gh<49?0:(gh<53?1:2))*3 + (gw<49?0:(gw<53?1:2));
            }
            #pragma unroll
            for (int tj=0;tj<4;tj++){
                const int j = tj*16 + lr;
                float lv = NEGV;
                if (i < 49 && j < 49){
                    const int ridx = (id - jdiv[tj] + 6)*13 + (im - jmod[tj] + 6);
                    lv = acc[ti][tj][reg]*SCALE_ + rel_table[ridx*6 + h]
                       + ((mi == mj[tj]) ? 0.f : NEGV);
                }
                acc[ti][tj][reg] = lv;
            }
        }
    }
    #pragma unroll
    for (int ti=0;ti<4;ti++){
        #pragma unroll
        for (int reg=0;reg<4;reg++){
            float mx = fmaxf(fmaxf(acc[ti][0][reg], acc[ti][1][reg]),
                             fmaxf(acc[ti][2][reg], acc[ti][3][reg]));
            #pragma unroll
            for (int o2=8;o2;o2>>=1) mx = fmaxf(mx, __shfl_xor(mx, o2, 64));
            float sum = 0.f;
            #pragma unroll
            for (int tj=0;tj<4;tj++){
                float p = __expf(acc[ti][tj][reg] - mx);
                acc[ti][tj][reg] = p;
                sum += p;
            }
            #pragma unroll
            for (int o2=8;o2;o2>>=1) sum += __shfl_xor(sum, o2, 64);
            const float rs = 1.f/sum;
            #pragma unroll
            for (int tj=0;tj<4;tj++) acc[ti][tj][reg] *= rs;
        }
    }
    #pragma unroll
    for (int ti=0;ti<4;ti++)
        #pragma unroll
        for (int tj=0;tj<4;tj++)
            #pragma unroll
            for (int reg=0;reg<4;reg++)
                pa[(ti*16 + lg*4 + reg)*72 + tj*16 + lr] = f2bu(acc[ti][tj][reg]);
    __syncthreads();

    fx4 oacc[4][2] = {};
    #pragma unroll
    for (int kk=0;kk<2;kk++){
        bf8 bfr[2];
        #pragma unroll
        for (int cd=0;cd<2;cd++)
            bfr[cd] = *(const bf8*)(vt + (cd*16+lr)*72 + kk*32 + lg*8);
        #pragma unroll
        for (int ti=0;ti<4;ti++){
            bf8 afr = *(const bf8*)(pa + (ti*16+lr)*72 + kk*32 + lg*8);
            #pragma unroll
            for (int cd=0;cd<2;cd++)
                oacc[ti][cd] = __builtin_amdgcn_mfma_f32_16x16x32_bf16(afr, bfr[cd], oacc[ti][cd], 0,0,0);
        }
    }
    u16* ob = o + (size_t)widx*49*192 + h*32;
    #pragma unroll
    for (int ti=0;ti<4;ti++)
        #pragma unroll
        for (int cd=0;cd<2;cd++)
            #pragma unroll
            for (int q=0;q<4;q++){
                const int i = ti*16 + lg*4 + q;
                if (i < 49) ob[(size_t)i*192 + cd*16 + lr] = f2bu(oacc[ti][cd][q]);
            }
}

extern "C" void kernel_launch(void* const* d_in, const int* in_sizes, int n_in,
                              void* d_out, int out_size, void* d_ws, size_t ws_size,
                              hipStream_t stream)
{
    const float* x      = (const float*)d_in[0];
    const float* ln1_g  = (const float*)d_in[1];
    const float* ln1_b  = (const float*)d_in[2];
    const float* qkv_w  = (const float*)d_in[3];
    const float* out_w  = (const float*)d_in[4];
    const float* out_b  = (const float*)d_in[5];
    const float* ln2_g  = (const float*)d_in[6];
    const float* ln2_b  = (const float*)d_in[7];
    const float* mlp_w1 = (const float*)d_in[8];
    const float* mlp_b1 = (const float*)d_in[9];
    const float* mlp_w2 = (const float*)d_in[10];
    const float* mlp_b2 = (const float*)d_in[11];
    const float* rel_t  = (const float*)d_in[12];

    char* ws = (char*)d_ws;
    u16*   Ybuf = (u16*)ws;                     // y / O / y2 bf16 [T,192]; later xw3 f32
    float* OutF = (float*)ws;
    u16*   XWbuf = (u16*)(ws + 154140672);      // xw / xw2 bf16 [T,192]
    u16*   QKVH  = (u16*)(ws + 231211008);      // qkv [T,576] then h [T,768] bf16
    u16*   Wq = (u16*)(ws + 539492352);
    u16*   Wo = Wq + 110592;
    u16*   W1 = Wo + 36864;
    u16*   W2 = W1 + 147456;

    f2b4_kernel<<<576,256,0,stream>>>(qkv_w, out_w, mlp_w1, mlp_w2, Wq, Wo, W1, W2);

    // partition + LN1
    partition_ln_kernel<<<3584,256,0,stream>>>(x, ln1_g, ln1_b, XWbuf, Ybuf);
    // qkv = y @ Wq^T : [T,576] bf16
    gemm_kernel<3,0,0,0,1,0><<<dim3(1568,3),256,0,stream>>>(Ybuf, Wq, nullptr, nullptr, QKVH,
                                                            nullptr, nullptr, nullptr, 576);
    attn_kernel<<<24576,64,0,stream>>>(QKVH, rel_t, Ybuf);
    // xw2 = xw + O @ Wo^T + b (bf16, in-place XW); y2 = LN2(xw2) -> Ybuf
    gemm_kernel<3,0,1,1,1,1><<<dim3(1568,1),256,0,stream>>>(Ybuf, Wo, out_b, XWbuf, XWbuf,
                                                            ln2_g, ln2_b, Ybuf, 192);
    // h = gelu(y2 @ W1^T + b1) : [T,768] bf16
    gemm_kernel<3,1,0,0,1,1><<<dim3(1568,4),256,0,stream>>>(Ybuf, W1, mlp_b1, nullptr, QKVH,
                                                            nullptr, nullptr, nullptr, 768);
    // xw3 = xw2 + h @ W2^T + b2 : f32 -> OutF
    gemm_kernel<12,0,1,0,0,1><<<dim3(1568,1),256,0,stream>>>(QKVH, W2, mlp_b2, XWbuf, OutF,
                                                             nullptr, nullptr, nullptr, 192);
    reverse_kernel<<<3584,256,0,stream>>>(OutF, (float*)d_out);
}

// Round 6
// 853.805 us; speedup vs baseline: 1.8190x; 1.0484x over previous
//
#include <hip/hip_runtime.h>
#include <hip/hip_bf16.h>

typedef unsigned short u16;
typedef unsigned int u32;
typedef __attribute__((ext_vector_type(4))) float fx4;
typedef __attribute__((ext_vector_type(8))) __bf16 bf8;

#define NEGV -1e9f
#define LOG2E 1.4426950408889634f
#define SCALE2 (0.17677669529663687f*1.4426950408889634f)

static __device__ __forceinline__ u16 f2bu(float f){
    __hip_bfloat16 h = __float2bfloat16(f);
    return *reinterpret_cast<u16*>(&h);
}
static __device__ __forceinline__ float b2f(u16 u){
    __hip_bfloat16 h;
    *reinterpret_cast<u16*>(&h) = u;
    return __bfloat162float(h);
}

// ---- K0: fp32 -> bf16 conversion of all 4 weight matrices ----
__global__ __launch_bounds__(256) void f2b4_kernel(
        const float* __restrict__ s0, const float* __restrict__ s1,
        const float* __restrict__ s2, const float* __restrict__ s3,
        u16* __restrict__ d0, u16* __restrict__ d1,
        u16* __restrict__ d2, u16* __restrict__ d3){
    int i = blockIdx.x*256 + threadIdx.x;
    if (i < 110592) d0[i] = f2bu(s0[i]);
    if (i < 36864)  d1[i] = f2bu(s1[i]);
    if (i < 147456){ d2[i] = f2bu(s2[i]); d3[i] = f2bu(s3[i]); }
}

// ---- fused logit table: LT[cls][h][64][64] = (rel_bias + shift_mask)*LOG2E, NEG pads ----
__global__ __launch_bounds__(256) void ltab_kernel(const float* __restrict__ rel_table,
                                                   float* __restrict__ LT){
    const int blk = blockIdx.x;           // cls*6 + h
    const int cls = blk/6, h = blk - cls*6;
    float* T = LT + blk*4096;
    for (int e = threadIdx.x; e < 4096; e += 256){
        const int i = e>>6, j = e&63;
        float v = NEGV;
        if (i < 49 && j < 49){
            const int id = i/7, im = i-id*7, jd = j/7, jm = j-jd*7;
            const int ridx = (id-jd+6)*13 + (im-jm+6);
            const float bias = rel_table[ridx*6 + h];
            const int ri = (cls&2) ? (id<4?1:2) : 0;
            const int rj = (cls&2) ? (jd<4?1:2) : 0;
            const int ci = (cls&1) ? (im<4?1:2) : 0;
            const int cj = (cls&1) ? (jm<4?1:2) : 0;
            v = bias + ((ri==rj && ci==cj) ? 0.f : NEGV);
        }
        T[e] = v * LOG2E;
    }
}

// ---- K1: roll(-3,-3) + window partition + LN1 ----
__global__ __launch_bounds__(256) void partition_ln_kernel(
        const float* __restrict__ x, const float* __restrict__ g, const float* __restrict__ bta,
        u16* __restrict__ xw, u16* __restrict__ y){
    __shared__ float lds[192*57];
    const int bi = blockIdx.x;
    const int b = bi/56, i = bi%56;
    const int si = (i+3)%56;
    const float* src = x + (size_t)b*602112 + (size_t)si*56;
    for (int e = threadIdx.x; e < 10752; e += 256){
        int c = e/56, j = e%56;
        lds[c*57 + j] = src[(size_t)c*3136 + j];
    }
    __syncthreads();
    const int wrow_base = (b*8 + i/7)*8;
    const int prow = (i%7)*7;
    for (int e = threadIdx.x; e < 10752; e += 256){
        int j = e/192, c = e%192;
        int t = (wrow_base + j/7)*49 + prow + (j%7);
        xw[(size_t)t*192 + c] = f2bu(lds[c*57 + (j+3)%56]);
    }
    const int wv = threadIdx.x>>6, l = threadIdx.x&63;
    for (int j = wv; j < 56; j += 4){
        const int jj = (j+3)%56;
        float v0 = lds[l*57 + jj], v1 = lds[(l+64)*57 + jj], v2 = lds[(l+128)*57 + jj];
        float s = v0+v1+v2;
        #pragma unroll
        for (int o=32;o;o>>=1) s += __shfl_xor(s, o, 64);
        const float mean = s*(1.f/192.f);
        float d0 = v0-mean, d1 = v1-mean, d2 = v2-mean;
        float qv = d0*d0 + d1*d1 + d2*d2;
        #pragma unroll
        for (int o=32;o;o>>=1) qv += __shfl_xor(qv, o, 64);
        const float rstd = rsqrtf(qv*(1.f/192.f) + 1e-5f);
        const int t = (wrow_base + j/7)*49 + prow + (j%7);
        u16* yr = y + (size_t)t*192;
        yr[l]     = f2bu(d0*rstd*g[l]     + bta[l]);
        yr[l+64]  = f2bu(d1*rstd*g[l+64]  + bta[l+64]);
        yr[l+128] = f2bu(d2*rstd*g[l+128] + bta[l+128]);
    }
}

// ---- K9: window reverse + roll(+3,+3) ----
__global__ __launch_bounds__(256) void reverse_kernel(const float* __restrict__ xw, float* __restrict__ out){
    __shared__ float lds[192*57];
    const int bi = blockIdx.x;
    const int b = bi/56, h = bi%56;
    const int i = (h+53)%56;
    const int wrow_base = (b*8 + i/7)*8;
    const int prow = (i%7)*7;
    for (int e = threadIdx.x; e < 10752; e += 256){
        int j = e/192, c = e%192;
        int t = (wrow_base + j/7)*49 + prow + (j%7);
        lds[c*57 + j] = xw[(size_t)t*192 + c];
    }
    __syncthreads();
    float* dst = out + (size_t)b*602112 + (size_t)h*56;
    for (int e = threadIdx.x; e < 10752; e += 256){
        int c = e/56, w = e%56;
        dst[(size_t)c*3136 + w] = lds[c*57 + (w+53)%56];
    }
}

// ---- staging: global -> LDS, 64-K-wide tile (128B/row), XOR-pre-swizzled source ----
template<int ROWS>
static __device__ __forceinline__ void stage_tile(const u16* __restrict__ g, size_t grow0,
                                                  int kc, int KE, u16* ldsbase, int tid){
    const int w = tid>>6, lane = tid&63;
    const int sub = lane>>3;
    const int b16 = (lane&7) ^ sub;
    #pragma unroll
    for (int i=0; i<ROWS/32; ++i){
        const int row = i*32 + w*8 + sub;
        const u16* src = g + (grow0+row)*(size_t)KE + kc*64 + b16*8;
        u16* dst = ldsbase + i*2048 + w*512;
#if __has_builtin(__builtin_amdgcn_global_load_lds)
        __builtin_amdgcn_global_load_lds(
            (const __attribute__((address_space(1))) u32*)src,
            (__attribute__((address_space(3))) u32*)dst, 16, 0, 0);
#else
        *(uint4*)(dst + lane*8) = *(const uint4*)src;
#endif
    }
}

static __device__ __forceinline__ bf8 rd_frag(const u16* lds, int row, int bbu){
    return *(const bf8*)(lds + row*64 + (bbu ^ ((row&7)<<3)));
}

// ---- pipelined GEMM: BM=128, BN=192, BK=64, double-buffered global_load_lds ----
template<int NK,int ACT,int RES,int LNOUT,int OUTBF,int HASB>
__global__ __launch_bounds__(256,2) void gemm_kernel(
    const u16* __restrict__ A, const u16* __restrict__ Bw,
    const float* __restrict__ bias, const u16* __restrict__ res,
    void* __restrict__ out,
    const float* __restrict__ lng, const float* __restrict__ lnb,
    u16* __restrict__ yout, int Ntot)
{
    const int K = NK*64;
    __shared__ __align__(16) u16 lds[40960];
    const int tid = threadIdx.x;
    const int wv = tid>>6, l = tid&63, lr = l&15, lg = l>>4;
    const int wm = wv&1, wn = wv>>1;
    const size_t row0 = (size_t)blockIdx.x*128;
    const int n0 = blockIdx.y*192;
    const u16* Bblk = Bw + (size_t)n0*K;

    stage_tile<128>(A, row0, 0, K, lds, tid);
    stage_tile<192>(Bblk, 0, 0, K, lds+16384, tid);
    __syncthreads();

    fx4 acc[4][6] = {};
    for (int kc=0; kc<NK; ++kc){
        const int cur = kc & 1;
        u16* Ac = cur ? (u16*)lds+8192  : (u16*)lds;
        u16* Bc = cur ? (u16*)lds+28672 : (u16*)lds+16384;
        if (kc+1 < NK){
            u16* An = cur ? (u16*)lds       : (u16*)lds+8192;
            u16* Bn = cur ? (u16*)lds+16384 : (u16*)lds+28672;
            stage_tile<128>(A, row0, kc+1, K, An, tid);
            stage_tile<192>(Bblk, 0, kc+1, K, Bn, tid);
        }
        #pragma unroll
        for (int kk=0; kk<2; ++kk){
            bf8 af[4], bfr[6];
            #pragma unroll
            for (int r=0;r<4;r++) af[r]  = rd_frag(Ac, wm*64 + r*16 + lr, kk*32 + lg*8);
            #pragma unroll
            for (int c=0;c<6;c++) bfr[c] = rd_frag(Bc, wn*96 + c*16 + lr, kk*32 + lg*8);
            #pragma unroll
            for (int r=0;r<4;r++)
                #pragma unroll
                for (int c=0;c<6;c++)
                    acc[r][c] = __builtin_amdgcn_mfma_f32_16x16x32_bf16(af[r], bfr[c], acc[r][c], 0,0,0);
        }
        __syncthreads();
    }

    #pragma unroll
    for (int r=0;r<4;r++)
        #pragma unroll
        for (int c=0;c<6;c++){
            const int col = n0 + wn*96 + c*16 + lr;
            const float bv = HASB ? bias[col] : 0.f;
            #pragma unroll
            for (int q=0;q<4;q++){
                const size_t grow = row0 + wm*64 + r*16 + lg*4 + q;
                float v = acc[r][c][q] + bv;
                if (ACT) v = 0.5f*v*(1.f + erff(v*0.70710678118654752f));
                if (RES) v += b2f(res[grow*Ntot + col]);
                acc[r][c][q] = v;
                if (OUTBF) ((u16*)out)[grow*Ntot + col] = f2bu(v);
                else       ((float*)out)[grow*Ntot + col] = v;
            }
        }
    if (LNOUT){
        float* redS = (float*)lds;
        #pragma unroll
        for (int r=0;r<4;r++)
            #pragma unroll
            for (int q=0;q<4;q++){
                float s  = 0.f, s2 = 0.f;
                #pragma unroll
                for (int c=0;c<6;c++){ float v = acc[r][c][q]; s += v; s2 += v*v; }
                #pragma unroll
                for (int o=8;o;o>>=1){ s += __shfl_xor(s, o, 64); s2 += __shfl_xor(s2, o, 64); }
                if (lr == 0){
                    const int rowl = wm*64 + r*16 + lg*4 + q;
                    redS[(wn*128 + rowl)*2 + 0] = s;
                    redS[(wn*128 + rowl)*2 + 1] = s2;
                }
            }
        __syncthreads();
        #pragma unroll
        for (int r=0;r<4;r++)
            #pragma unroll
            for (int q=0;q<4;q++){
                const int rowl = wm*64 + r*16 + lg*4 + q;
                const float S  = redS[rowl*2+0] + redS[(128+rowl)*2+0];
                const float S2 = redS[rowl*2+1] + redS[(128+rowl)*2+1];
                const float mean = S*(1.f/192.f);
                const float rstd = rsqrtf(S2*(1.f/192.f) - mean*mean + 1e-5f);
                const size_t grow = row0 + rowl;
                #pragma unroll
                for (int c=0;c<6;c++){
                    const int col = wn*96 + c*16 + lr;
                    yout[grow*192 + col] = f2bu((acc[r][c][q]-mean)*rstd*lng[col] + lnb[col]);
                }
            }
    }
}

// ---- attention: one wave per (window, head), fused logit table ----
__global__ __launch_bounds__(64) void attn_kernel(const u16* __restrict__ qkv,
                                                  const float* __restrict__ LT,
                                                  u16* __restrict__ o)
{
    __shared__ u16 pa[64*72];
    __shared__ u16 vt[32*72];
    const int bid = blockIdx.x;
    const int widx = bid/6, h = bid - widx*6;
    const int wi = widx & 63;
    const int nhi = wi>>3, nwi = wi&7;
    const int l = threadIdx.x, lr = l&15, lg = l>>4;
    const u16* base = qkv + (size_t)widx*49*576;
    const int cls = ((nhi==7)?2:0) | ((nwi==7)?1:0);
    const float* Th = LT + (size_t)(cls*6 + h)*4096;

    bf8 qf[4], kf[4];
    #pragma unroll
    for (int t=0;t<4;t++){
        const int row = min(t*16 + lr, 48);
        qf[t] = *(const bf8*)(base + (size_t)row*576 + h*32 + lg*8);
        kf[t] = *(const bf8*)(base + (size_t)row*576 + 192 + h*32 + lg*8);
    }
    for (int e=l; e<480; e+=64){
        int d = e/15, j = 49 + (e - d*15);
        vt[d*72 + j] = 0;
    }
    for (int e=l; e<784; e+=64){
        int j = e>>4, dp = e&15;
        u32 val = *(const u32*)(base + (size_t)j*576 + 384 + h*32 + dp*2);
        vt[(dp*2)*72 + j]   = (u16)(val & 0xffffu);
        vt[(dp*2+1)*72 + j] = (u16)(val >> 16);
    }

    fx4 acc[4][4] = {};
    #pragma unroll
    for (int ti=0;ti<4;ti++)
        #pragma unroll
        for (int tj=0;tj<4;tj++)
            acc[ti][tj] = __builtin_amdgcn_mfma_f32_16x16x32_bf16(qf[ti], kf[tj], acc[ti][tj], 0,0,0);

    // logits = qk*SCALE2 + LT[i][j]  (table already includes bias+mask+pads, *LOG2E)
    #pragma unroll
    for (int ti=0;ti<4;ti++){
        #pragma unroll
        for (int reg=0;reg<4;reg++){
            const int i = ti*16 + lg*4 + reg;
            const float* rowp = Th + i*64;
            #pragma unroll
            for (int tj=0;tj<4;tj++)
                acc[ti][tj][reg] = fmaf(acc[ti][tj][reg], SCALE2, rowp[tj*16 + lr]);
        }
    }
    // row softmax in base-2
    #pragma unroll
    for (int ti=0;ti<4;ti++){
        #pragma unroll
        for (int reg=0;reg<4;reg++){
            float mx = fmaxf(fmaxf(acc[ti][0][reg], acc[ti][1][reg]),
                             fmaxf(acc[ti][2][reg], acc[ti][3][reg]));
            #pragma unroll
            for (int o2=8;o2;o2>>=1) mx = fmaxf(mx, __shfl_xor(mx, o2, 64));
            float sum = 0.f;
            #pragma unroll
            for (int tj=0;tj<4;tj++){
                float p = __builtin_amdgcn_exp2f(acc[ti][tj][reg] - mx);
                acc[ti][tj][reg] = p;
                sum += p;
            }
            #pragma unroll
            for (int o2=8;o2;o2>>=1) sum += __shfl_xor(sum, o2, 64);
            const float rs = 1.f/sum;
            #pragma unroll
            for (int tj=0;tj<4;tj++) acc[ti][tj][reg] *= rs;
        }
    }
    #pragma unroll
    for (int ti=0;ti<4;ti++)
        #pragma unroll
        for (int tj=0;tj<4;tj++)
            #pragma unroll
            for (int reg=0;reg<4;reg++)
                pa[(ti*16 + lg*4 + reg)*72 + tj*16 + lr] = f2bu(acc[ti][tj][reg]);
    __syncthreads();

    fx4 oacc[4][2] = {};
    #pragma unroll
    for (int kk=0;kk<2;kk++){
        bf8 bfr[2];
        #pragma unroll
        for (int cd=0;cd<2;cd++)
            bfr[cd] = *(const bf8*)(vt + (cd*16+lr)*72 + kk*32 + lg*8);
        #pragma unroll
        for (int ti=0;ti<4;ti++){
            bf8 afr = *(const bf8*)(pa + (ti*16+lr)*72 + kk*32 + lg*8);
            #pragma unroll
            for (int cd=0;cd<2;cd++)
                oacc[ti][cd] = __builtin_amdgcn_mfma_f32_16x16x32_bf16(afr, bfr[cd], oacc[ti][cd], 0,0,0);
        }
    }
    u16* ob = o + (size_t)widx*49*192 + h*32;
    #pragma unroll
    for (int ti=0;ti<4;ti++)
        #pragma unroll
        for (int cd=0;cd<2;cd++)
            #pragma unroll
            for (int q=0;q<4;q++){
                const int i = ti*16 + lg*4 + q;
                if (i < 49) ob[(size_t)i*192 + cd*16 + lr] = f2bu(oacc[ti][cd][q]);
            }
}

extern "C" void kernel_launch(void* const* d_in, const int* in_sizes, int n_in,
                              void* d_out, int out_size, void* d_ws, size_t ws_size,
                              hipStream_t stream)
{
    const float* x      = (const float*)d_in[0];
    const float* ln1_g  = (const float*)d_in[1];
    const float* ln1_b  = (const float*)d_in[2];
    const float* qkv_w  = (const float*)d_in[3];
    const float* out_w  = (const float*)d_in[4];
    const float* out_b  = (const float*)d_in[5];
    const float* ln2_g  = (const float*)d_in[6];
    const float* ln2_b  = (const float*)d_in[7];
    const float* mlp_w1 = (const float*)d_in[8];
    const float* mlp_b1 = (const float*)d_in[9];
    const float* mlp_w2 = (const float*)d_in[10];
    const float* mlp_b2 = (const float*)d_in[11];
    const float* rel_t  = (const float*)d_in[12];

    char* ws = (char*)d_ws;
    u16*   Ybuf = (u16*)ws;                     // y / O / y2 bf16 [T,192]; later xw3 f32
    float* OutF = (float*)ws;
    float* LTab = (float*)(ws + 77070336);      // [4][6][64][64] f32 (overwritten by OutF after attn)
    u16*   XWbuf = (u16*)(ws + 154140672);      // xw / xw2 bf16 [T,192]
    u16*   QKVH  = (u16*)(ws + 231211008);      // qkv [T,576] then h [T,768] bf16
    u16*   Wq = (u16*)(ws + 539492352);
    u16*   Wo = Wq + 110592;
    u16*   W1 = Wo + 36864;
    u16*   W2 = W1 + 147456;

    f2b4_kernel<<<576,256,0,stream>>>(qkv_w, out_w, mlp_w1, mlp_w2, Wq, Wo, W1, W2);
    ltab_kernel<<<24,256,0,stream>>>(rel_t, LTab);

    // partition + LN1
    partition_ln_kernel<<<3584,256,0,stream>>>(x, ln1_g, ln1_b, XWbuf, Ybuf);
    // qkv = y @ Wq^T : [T,576] bf16
    gemm_kernel<3,0,0,0,1,0><<<dim3(1568,3),256,0,stream>>>(Ybuf, Wq, nullptr, nullptr, QKVH,
                                                            nullptr, nullptr, nullptr, 576);
    attn_kernel<<<24576,64,0,stream>>>(QKVH, LTab, Ybuf);
    // xw2 = xw + O @ Wo^T + b (bf16, in-place XW); y2 = LN2(xw2) -> Ybuf
    gemm_kernel<3,0,1,1,1,1><<<dim3(1568,1),256,0,stream>>>(Ybuf, Wo, out_b, XWbuf, XWbuf,
                                                            ln2_g, ln2_b, Ybuf, 192);
    // h = gelu(y2 @ W1^T + b1) : [T,768] bf16
    gemm_kernel<3,1,0,0,1,1><<<dim3(1568,4),256,0,stream>>>(Ybuf, W1, mlp_b1, nullptr, QKVH,
                                                            nullptr, nullptr, nullptr, 768);
    // xw3 = xw2 + h @ W2^T + b2 : f32 -> OutF
    gemm_kernel<12,0,1,0,0,1><<<dim3(1568,1),256,0,stream>>>(QKVH, W2, mlp_b2, XWbuf, OutF,
                                                             nullptr, nullptr, nullptr, 192);
    reverse_kernel<<<3584,256,0,stream>>>(OutF, (float*)d_out);
}

// Round 7
// 769.033 us; speedup vs baseline: 2.0195x; 1.1102x over previous
//
#include <hip/hip_runtime.h>
#include <hip/hip_bf16.h>
#include <hip/hip_fp8.h>

typedef unsigned short u16;
typedef unsigned int u32;
typedef unsigned char u8;
typedef __attribute__((ext_vector_type(4))) float fx4;
typedef __attribute__((ext_vector_type(8))) __bf16 bf8;

#define NEGV -1e9f
#define LOG2E 1.4426950408889634f
#define SCALE2 (0.17677669529663687f*1.4426950408889634f)

static __device__ __forceinline__ u16 f2bu(float f){
    __hip_bfloat16 h = __float2bfloat16(f);
    return *reinterpret_cast<u16*>(&h);
}
static __device__ __forceinline__ float b2f(u16 u){
    __hip_bfloat16 h;
    *reinterpret_cast<u16*>(&h) = u;
    return __bfloat162float(h);
}
static __device__ __forceinline__ u8 f2f8(float v){
    __hip_fp8_e4m3 t(v);
    return *reinterpret_cast<u8*>(&t);
}
// exact-erf GELU via A&S 7.1.26 (|err| <= 1.5e-7): 1 exp2 + 1 div
static __device__ __forceinline__ float gelu_f(float v){
    const float z = v*0.70710678118654752f;
    const float x = fabsf(z);
    const float t = 1.f/(1.f + 0.3275911f*x);
    const float p = t*(0.254829592f + t*(-0.284496736f + t*(1.421413741f
                   + t*(-1.453152027f + t*1.061405429f))));
    float er = 1.f - p*__builtin_amdgcn_exp2f(-x*x*LOG2E);
    er = (z < 0.f) ? -er : er;
    return 0.5f*v*(1.f + er);
}

// ---- K0: weight conversion: Wq,Wo,W1 -> bf16 ; W2*16 -> fp8 e4m3 ----
__global__ __launch_bounds__(256) void f2b4_kernel(
        const float* __restrict__ s0, const float* __restrict__ s1,
        const float* __restrict__ s2, const float* __restrict__ s3,
        u16* __restrict__ d0, u16* __restrict__ d1,
        u16* __restrict__ d2, u8* __restrict__ d3){
    int i = blockIdx.x*256 + threadIdx.x;
    if (i < 110592) d0[i] = f2bu(s0[i]);
    if (i < 36864)  d1[i] = f2bu(s1[i]);
    if (i < 147456){ d2[i] = f2bu(s2[i]); d3[i] = f2f8(s3[i]*16.f); }
}

// ---- fused logit table: LT[cls][h][64][64] = (rel_bias + shift_mask)*LOG2E, NEG pads ----
__global__ __launch_bounds__(256) void ltab_kernel(const float* __restrict__ rel_table,
                                                   float* __restrict__ LT){
    const int blk = blockIdx.x;           // cls*6 + h
    const int cls = blk/6, h = blk - cls*6;
    float* T = LT + blk*4096;
    for (int e = threadIdx.x; e < 4096; e += 256){
        const int i = e>>6, j = e&63;
        float v = NEGV;
        if (i < 49 && j < 49){
            const int id = i/7, im = i-id*7, jd = j/7, jm = j-jd*7;
            const int ridx = (id-jd+6)*13 + (im-jm+6);
            const float bias = rel_table[ridx*6 + h];
            const int ri = (cls&2) ? (id<4?1:2) : 0;
            const int rj = (cls&2) ? (jd<4?1:2) : 0;
            const int ci = (cls&1) ? (im<4?1:2) : 0;
            const int cj = (cls&1) ? (jm<4?1:2) : 0;
            v = bias + ((ri==rj && ci==cj) ? 0.f : NEGV);
        }
        T[e] = v * LOG2E;
    }
}

// ---- K1: roll(-3,-3) + window partition + LN1 ----
__global__ __launch_bounds__(256) void partition_ln_kernel(
        const float* __restrict__ x, const float* __restrict__ g, const float* __restrict__ bta,
        u16* __restrict__ xw, u16* __restrict__ y){
    __shared__ float lds[192*57];
    const int bi = blockIdx.x;
    const int b = bi/56, i = bi%56;
    const int si = (i+3)%56;
    const float* src = x + (size_t)b*602112 + (size_t)si*56;
    for (int e = threadIdx.x; e < 10752; e += 256){
        int c = e/56, j = e%56;
        lds[c*57 + j] = src[(size_t)c*3136 + j];
    }
    __syncthreads();
    const int wrow_base = (b*8 + i/7)*8;
    const int prow = (i%7)*7;
    for (int e = threadIdx.x; e < 10752; e += 256){
        int j = e/192, c = e%192;
        int t = (wrow_base + j/7)*49 + prow + (j%7);
        xw[(size_t)t*192 + c] = f2bu(lds[c*57 + (j+3)%56]);
    }
    const int wv = threadIdx.x>>6, l = threadIdx.x&63;
    for (int j = wv; j < 56; j += 4){
        const int jj = (j+3)%56;
        float v0 = lds[l*57 + jj], v1 = lds[(l+64)*57 + jj], v2 = lds[(l+128)*57 + jj];
        float s = v0+v1+v2;
        #pragma unroll
        for (int o=32;o;o>>=1) s += __shfl_xor(s, o, 64);
        const float mean = s*(1.f/192.f);
        float d0 = v0-mean, d1 = v1-mean, d2 = v2-mean;
        float qv = d0*d0 + d1*d1 + d2*d2;
        #pragma unroll
        for (int o=32;o;o>>=1) qv += __shfl_xor(qv, o, 64);
        const float rstd = rsqrtf(qv*(1.f/192.f) + 1e-5f);
        const int t = (wrow_base + j/7)*49 + prow + (j%7);
        u16* yr = y + (size_t)t*192;
        yr[l]     = f2bu(d0*rstd*g[l]     + bta[l]);
        yr[l+64]  = f2bu(d1*rstd*g[l+64]  + bta[l+64]);
        yr[l+128] = f2bu(d2*rstd*g[l+128] + bta[l+128]);
    }
}

// ---- K9: window reverse + roll(+3,+3): xw3[200704,192] bf16 -> out f32 ----
__global__ __launch_bounds__(256) void reverse_kernel(const u16* __restrict__ xw, float* __restrict__ out){
    __shared__ float lds[192*57];
    const int bi = blockIdx.x;
    const int b = bi/56, h = bi%56;
    const int i = (h+53)%56;
    const int wrow_base = (b*8 + i/7)*8;
    const int prow = (i%7)*7;
    for (int e = threadIdx.x; e < 10752; e += 256){
        int j = e/192, c = e%192;
        int t = (wrow_base + j/7)*49 + prow + (j%7);
        lds[c*57 + j] = b2f(xw[(size_t)t*192 + c]);
    }
    __syncthreads();
    float* dst = out + (size_t)b*602112 + (size_t)h*56;
    for (int e = threadIdx.x; e < 10752; e += 256){
        int c = e/56, w = e%56;
        dst[(size_t)c*3136 + w] = lds[c*57 + (w+53)%56];
    }
}

// ---- staging: global -> LDS, 128-byte-wide tile rows, XOR-pre-swizzled source ----
template<int ROWS>
static __device__ __forceinline__ void stage_tile(const char* __restrict__ g, size_t row0,
                                                  int kc, int pitch, u16* ldsbase, int tid){
    const int w = tid>>6, lane = tid&63;
    const int sub = lane>>3;
    const int b16 = (lane&7) ^ sub;
    #pragma unroll
    for (int i=0; i<ROWS/32; ++i){
        const int row = i*32 + w*8 + sub;
        const char* src = g + (row0+row)*(size_t)pitch + (size_t)kc*128 + b16*16;
        u16* dst = ldsbase + i*2048 + w*512;
#if __has_builtin(__builtin_amdgcn_global_load_lds)
        __builtin_amdgcn_global_load_lds(
            (const __attribute__((address_space(1))) u32*)src,
            (__attribute__((address_space(3))) u32*)dst, 16, 0, 0);
#else
        *(uint4*)(dst + lane*8) = *(const uint4*)src;
#endif
    }
}

static __device__ __forceinline__ bf8 rd_frag16(const u16* lds, int row, int boff){
    const char* p = (const char*)lds + row*128 + (boff ^ ((row&7)<<4));
    return *(const bf8*)p;
}
static __device__ __forceinline__ long rd_frag8(const u16* lds, int row, int boff){
    const char* p = (const char*)lds + row*128 + (boff ^ ((row&7)<<4));
    return *(const long*)p;
}

// ---- pipelined GEMM: BM=128, BN=192, 128B K-chunks, double-buffered global_load_lds ----
// ESZ: element size of A and B (2=bf16, 1=fp8 e4m3). OUT: 1=bf16, 2=fp8.
// ascale multiplies the accumulator before bias (for fp8 weight scaling).
template<int KEL,int ESZ,int ACT,int RES,int LNOUT,int OUT,int HASB>
__global__ __launch_bounds__(256,2) void gemm_kernel(
    const void* __restrict__ Av, const void* __restrict__ Bv,
    const float* __restrict__ bias, const u16* __restrict__ res,
    void* __restrict__ out,
    const float* __restrict__ lng, const float* __restrict__ lnb,
    u16* __restrict__ yout, int Ntot, float ascale)
{
    constexpr int NKT = (KEL*ESZ)/128;
    constexpr int KKS = (ESZ==1)?4:2;
    constexpr int PITCH = KEL*ESZ;
    __shared__ __align__(16) u16 lds[40960];
    const int tid = threadIdx.x;
    const int wv = tid>>6, l = tid&63, lr = l&15, lg = l>>4;
    const int wm = wv&1, wn = wv>>1;
    const size_t row0 = (size_t)blockIdx.x*128;
    const int n0 = blockIdx.y*192;
    const char* A = (const char*)Av;
    const char* Bblk = (const char*)Bv + (size_t)n0*PITCH;

    stage_tile<128>(A, row0, 0, PITCH, lds, tid);
    stage_tile<192>(Bblk, 0, 0, PITCH, lds+16384, tid);
    __syncthreads();

    fx4 acc[4][6] = {};
    for (int kc=0; kc<NKT; ++kc){
        const int cur = kc & 1;
        u16* Ac = cur ? (u16*)lds+8192  : (u16*)lds;
        u16* Bc = cur ? (u16*)lds+28672 : (u16*)lds+16384;
        if (kc+1 < NKT){
            u16* An = cur ? (u16*)lds       : (u16*)lds+8192;
            u16* Bn = cur ? (u16*)lds+16384 : (u16*)lds+28672;
            stage_tile<128>(A, row0, kc+1, PITCH, An, tid);
            stage_tile<192>(Bblk, 0, kc+1, PITCH, Bn, tid);
        }
        #pragma unroll
        for (int kk=0; kk<KKS; ++kk){
            if constexpr (ESZ==2){
                bf8 af[4], bfr[6];
                #pragma unroll
                for (int r=0;r<4;r++) af[r]  = rd_frag16(Ac, wm*64 + r*16 + lr, kk*64 + lg*16);
                #pragma unroll
                for (int c=0;c<6;c++) bfr[c] = rd_frag16(Bc, wn*96 + c*16 + lr, kk*64 + lg*16);
                #pragma unroll
                for (int r=0;r<4;r++)
                    #pragma unroll
                    for (int c=0;c<6;c++)
                        acc[r][c] = __builtin_amdgcn_mfma_f32_16x16x32_bf16(af[r], bfr[c], acc[r][c], 0,0,0);
            } else {
                long af[4], bfr[6];
                #pragma unroll
                for (int r=0;r<4;r++) af[r]  = rd_frag8(Ac, wm*64 + r*16 + lr, kk*32 + lg*8);
                #pragma unroll
                for (int c=0;c<6;c++) bfr[c] = rd_frag8(Bc, wn*96 + c*16 + lr, kk*32 + lg*8);
                #pragma unroll
                for (int r=0;r<4;r++)
                    #pragma unroll
                    for (int c=0;c<6;c++)
                        acc[r][c] = __builtin_amdgcn_mfma_f32_16x16x32_fp8_fp8(af[r], bfr[c], acc[r][c], 0,0,0);
            }
        }
        __syncthreads();
    }

    #pragma unroll
    for (int r=0;r<4;r++)
        #pragma unroll
        for (int c=0;c<6;c++){
            const int col = n0 + wn*96 + c*16 + lr;
            const float bv = HASB ? bias[col] : 0.f;
            #pragma unroll
            for (int q=0;q<4;q++){
                const size_t grow = row0 + wm*64 + r*16 + lg*4 + q;
                float v = fmaf(acc[r][c][q], ascale, bv);
                if (ACT) v = gelu_f(v);
                if (RES) v += b2f(res[grow*Ntot + col]);
                acc[r][c][q] = v;
                if (OUT==1) ((u16*)out)[grow*Ntot + col] = f2bu(v);
                else        ((u8*)out)[grow*(size_t)Ntot + col] = f2f8(v);
            }
        }
    if (LNOUT){
        float* redS = (float*)lds;
        #pragma unroll
        for (int r=0;r<4;r++)
            #pragma unroll
            for (int q=0;q<4;q++){
                float s  = 0.f, s2 = 0.f;
                #pragma unroll
                for (int c=0;c<6;c++){ float v = acc[r][c][q]; s += v; s2 += v*v; }
                #pragma unroll
                for (int o=8;o;o>>=1){ s += __shfl_xor(s, o, 64); s2 += __shfl_xor(s2, o, 64); }
                if (lr == 0){
                    const int rowl = wm*64 + r*16 + lg*4 + q;
                    redS[(wn*128 + rowl)*2 + 0] = s;
                    redS[(wn*128 + rowl)*2 + 1] = s2;
                }
            }
        __syncthreads();
        #pragma unroll
        for (int r=0;r<4;r++)
            #pragma unroll
            for (int q=0;q<4;q++){
                const int rowl = wm*64 + r*16 + lg*4 + q;
                const float S  = redS[rowl*2+0] + redS[(128+rowl)*2+0];
                const float S2 = redS[rowl*2+1] + redS[(128+rowl)*2+1];
                const float mean = S*(1.f/192.f);
                const float rstd = rsqrtf(S2*(1.f/192.f) - mean*mean + 1e-5f);
                const size_t grow = row0 + rowl;
                #pragma unroll
                for (int c=0;c<6;c++){
                    const int col = wn*96 + c*16 + lr;
                    yout[grow*192 + col] = f2bu((acc[r][c][q]-mean)*rstd*lng[col] + lnb[col]);
                }
            }
    }
}

// ---- attention: one wave per (window, head), fused logit table ----
__global__ __launch_bounds__(64) void attn_kernel(const u16* __restrict__ qkv,
                                                  const float* __restrict__ LT,
                                                  u16* __restrict__ o)
{
    __shared__ u16 pa[64*72];
    __shared__ u16 vt[32*72];
    const int bid = blockIdx.x;
    const int widx = bid/6, h = bid - widx*6;
    const int wi = widx & 63;
    const int nhi = wi>>3, nwi = wi&7;
    const int l = threadIdx.x, lr = l&15, lg = l>>4;
    const u16* base = qkv + (size_t)widx*49*576;
    const int cls = ((nhi==7)?2:0) | ((nwi==7)?1:0);
    const float* Th = LT + (size_t)(cls*6 + h)*4096;

    bf8 qf[4], kf[4];
    #pragma unroll
    for (int t=0;t<4;t++){
        const int row = min(t*16 + lr, 48);
        qf[t] = *(const bf8*)(base + (size_t)row*576 + h*32 + lg*8);
        kf[t] = *(const bf8*)(base + (size_t)row*576 + 192 + h*32 + lg*8);
    }
    for (int e=l; e<480; e+=64){
        int d = e/15, j = 49 + (e - d*15);
        vt[d*72 + j] = 0;
    }
    for (int e=l; e<784; e+=64){
        int j = e>>4, dp = e&15;
        u32 val = *(const u32*)(base + (size_t)j*576 + 384 + h*32 + dp*2);
        vt[(dp*2)*72 + j]   = (u16)(val & 0xffffu);
        vt[(dp*2+1)*72 + j] = (u16)(val >> 16);
    }

    fx4 acc[4][4] = {};
    #pragma unroll
    for (int ti=0;ti<4;ti++)
        #pragma unroll
        for (int tj=0;tj<4;tj++)
            acc[ti][tj] = __builtin_amdgcn_mfma_f32_16x16x32_bf16(qf[ti], kf[tj], acc[ti][tj], 0,0,0);

    #pragma unroll
    for (int ti=0;ti<4;ti++){
        #pragma unroll
        for (int reg=0;reg<4;reg++){
            const int i = ti*16 + lg*4 + reg;
            const float* rowp = Th + i*64;
            #pragma unroll
            for (int tj=0;tj<4;tj++)
                acc[ti][tj][reg] = fmaf(acc[ti][tj][reg], SCALE2, rowp[tj*16 + lr]);
        }
    }
    #pragma unroll
    for (int ti=0;ti<4;ti++){
        #pragma unroll
        for (int reg=0;reg<4;reg++){
            float mx = fmaxf(fmaxf(acc[ti][0][reg], acc[ti][1][reg]),
                             fmaxf(acc[ti][2][reg], acc[ti][3][reg]));
            #pragma unroll
            for (int o2=8;o2;o2>>=1) mx = fmaxf(mx, __shfl_xor(mx, o2, 64));
            float sum = 0.f;
            #pragma unroll
            for (int tj=0;tj<4;tj++){
                float p = __builtin_amdgcn_exp2f(acc[ti][tj][reg] - mx);
                acc[ti][tj][reg] = p;
                sum += p;
            }
            #pragma unroll
            for (int o2=8;o2;o2>>=1) sum += __shfl_xor(sum, o2, 64);
            const float rs = 1.f/sum;
            #pragma unroll
            for (int tj=0;tj<4;tj++) acc[ti][tj][reg] *= rs;
        }
    }
    #pragma unroll
    for (int ti=0;ti<4;ti++)
        #pragma unroll
        for (int tj=0;tj<4;tj++)
            #pragma unroll
            for (int reg=0;reg<4;reg++)
                pa[(ti*16 + lg*4 + reg)*72 + tj*16 + lr] = f2bu(acc[ti][tj][reg]);
    __syncthreads();

    fx4 oacc[4][2] = {};
    #pragma unroll
    for (int kk=0;kk<2;kk++){
        bf8 bfr[2];
        #pragma unroll
        for (int cd=0;cd<2;cd++)
            bfr[cd] = *(const bf8*)(vt + (cd*16+lr)*72 + kk*32 + lg*8);
        #pragma unroll
        for (int ti=0;ti<4;ti++){
            bf8 afr = *(const bf8*)(pa + (ti*16+lr)*72 + kk*32 + lg*8);
            #pragma unroll
            for (int cd=0;cd<2;cd++)
                oacc[ti][cd] = __builtin_amdgcn_mfma_f32_16x16x32_bf16(afr, bfr[cd], oacc[ti][cd], 0,0,0);
        }
    }
    u16* ob = o + (size_t)widx*49*192 + h*32;
    #pragma unroll
    for (int ti=0;ti<4;ti++)
        #pragma unroll
        for (int cd=0;cd<2;cd++)
            #pragma unroll
            for (int q=0;q<4;q++){
                const int i = ti*16 + lg*4 + q;
                if (i < 49) ob[(size_t)i*192 + cd*16 + lr] = f2bu(oacc[ti][cd][q]);
            }
}

extern "C" void kernel_launch(void* const* d_in, const int* in_sizes, int n_in,
                              void* d_out, int out_size, void* d_ws, size_t ws_size,
                              hipStream_t stream)
{
    const float* x      = (const float*)d_in[0];
    const float* ln1_g  = (const float*)d_in[1];
    const float* ln1_b  = (const float*)d_in[2];
    const float* qkv_w  = (const float*)d_in[3];
    const float* out_w  = (const float*)d_in[4];
    const float* out_b  = (const float*)d_in[5];
    const float* ln2_g  = (const float*)d_in[6];
    const float* ln2_b  = (const float*)d_in[7];
    const float* mlp_w1 = (const float*)d_in[8];
    const float* mlp_b1 = (const float*)d_in[9];
    const float* mlp_w2 = (const float*)d_in[10];
    const float* mlp_b2 = (const float*)d_in[11];
    const float* rel_t  = (const float*)d_in[12];

    char* ws = (char*)d_ws;
    u16*   Ybuf = (u16*)ws;                     // y / O / y2 / xw3 bf16 [T,192]
    float* LTab = (float*)(ws + 77070336);      // [4][6][64][64] f32
    u16*   XWbuf = (u16*)(ws + 154140672);      // xw / xw2 bf16 [T,192]
    u16*   QKVH  = (u16*)(ws + 231211008);      // qkv bf16 [T,576]; then h fp8 [T,768]
    u8*    Hbuf  = (u8*)(ws + 231211008);
    u16*   Wq = (u16*)(ws + 539492352);
    u16*   Wo = Wq + 110592;
    u16*   W1 = Wo + 36864;
    u8*    W2f8 = (u8*)(W1 + 147456);

    f2b4_kernel<<<576,256,0,stream>>>(qkv_w, out_w, mlp_w1, mlp_w2, Wq, Wo, W1, W2f8);
    ltab_kernel<<<24,256,0,stream>>>(rel_t, LTab);

    // partition + LN1
    partition_ln_kernel<<<3584,256,0,stream>>>(x, ln1_g, ln1_b, XWbuf, Ybuf);
    // qkv = y @ Wq^T : [T,576] bf16
    gemm_kernel<192,2,0,0,0,1,0><<<dim3(1568,3),256,0,stream>>>(Ybuf, Wq, nullptr, nullptr, QKVH,
                                                                nullptr, nullptr, nullptr, 576, 1.f);
    attn_kernel<<<24576,64,0,stream>>>(QKVH, LTab, Ybuf);
    // xw2 = xw + O @ Wo^T + b (bf16, in-place XW); y2 = LN2(xw2) -> Ybuf
    gemm_kernel<192,2,0,1,1,1,1><<<dim3(1568,1),256,0,stream>>>(Ybuf, Wo, out_b, XWbuf, XWbuf,
                                                                ln2_g, ln2_b, Ybuf, 192, 1.f);
    // h = gelu(y2 @ W1^T + b1) : [T,768] fp8 e4m3
    gemm_kernel<192,2,1,0,0,2,1><<<dim3(1568,4),256,0,stream>>>(Ybuf, W1, mlp_b1, nullptr, Hbuf,
                                                                nullptr, nullptr, nullptr, 768, 1.f);
    // xw3 = xw2 + (h @ W2f8^T)/16 + b2 : bf16 -> Ybuf
    gemm_kernel<768,1,0,1,0,1,1><<<dim3(1568,1),256,0,stream>>>(Hbuf, W2f8, mlp_b2, XWbuf, Ybuf,
                                                                nullptr, nullptr, nullptr, 192, 0.0625f);
    reverse_kernel<<<3584,256,0,stream>>>(Ybuf, (float*)d_out);
}